// Round 1
// baseline (1453.927 us; speedup 1.0000x reference)
//
#include <hip/hip_runtime.h>
#include <math.h>

#define BB 2
#define TT 2048
#define CC 768
#define HH 12
#define HD 64
#define N3 (3*CC)

// ---------------------------------------------------------------------------
// GEMM 1: qkv = x @ Wqkv + bqkv, scattered to q/k/v in [B,H,T,HD] layout.
// A = x [4096 x 768] row-major, B = Wqkv [768 x 2304] row-major.
// 128x128 tile, BK=8, 256 threads, 8x8 micro-tile.
// ---------------------------------------------------------------------------
__global__ __launch_bounds__(256)
void athena_gemm_qkv(const float* __restrict__ x, const float* __restrict__ W,
                     const float* __restrict__ bias,
                     float* __restrict__ qout, float* __restrict__ kout,
                     float* __restrict__ vout)
{
    const int K = CC;        // 768
    const int N = N3;        // 2304

    __shared__ float As[8][132];   // [k][m], padded
    __shared__ float Bs[8][132];   // [k][n], padded

    const int tid = threadIdx.x;
    const int m0 = blockIdx.y * 128;
    const int n0 = blockIdx.x * 128;

    const int tx = tid & 15;
    const int ty = tid >> 4;

    // A staging: thread -> row ar, k-offset ac (4 floats)
    const int ar = tid >> 1;
    const int ac = (tid & 1) * 4;
    // B staging: thread -> k-row br, col bc (4 floats)
    const int br = tid >> 5;
    const int bc = (tid & 31) * 4;

    const float* Aptr = x + (size_t)(m0 + ar) * K + ac;
    const float* Bptr = W + (size_t)br * N + n0 + bc;

    float acc[8][8];
    #pragma unroll
    for (int i = 0; i < 8; ++i)
        #pragma unroll
        for (int j = 0; j < 8; ++j) acc[i][j] = 0.f;

    for (int k0 = 0; k0 < K; k0 += 8) {
        float4 av = *(const float4*)(Aptr + k0);
        float4 bv = *(const float4*)(Bptr + (size_t)k0 * N);
        __syncthreads();
        As[ac + 0][ar] = av.x;
        As[ac + 1][ar] = av.y;
        As[ac + 2][ar] = av.z;
        As[ac + 3][ar] = av.w;
        *(float4*)&Bs[br][bc] = bv;
        __syncthreads();
        #pragma unroll
        for (int kk = 0; kk < 8; ++kk) {
            float a[8], b[8];
            *(float4*)&a[0] = *(const float4*)&As[kk][ty * 8];
            *(float4*)&a[4] = *(const float4*)&As[kk][ty * 8 + 4];
            *(float4*)&b[0] = *(const float4*)&Bs[kk][tx * 8];
            *(float4*)&b[4] = *(const float4*)&Bs[kk][tx * 8 + 4];
            #pragma unroll
            for (int i = 0; i < 8; ++i)
                #pragma unroll
                for (int j = 0; j < 8; ++j)
                    acc[i][j] += a[i] * b[j];
        }
    }

    // epilogue: bias + scatter into q/k/v [B*H, T, 64]
    const int which = n0 / CC;                 // constant per block (768 = 6*128)
    float* dst = (which == 0) ? qout : (which == 1 ? kout : vout);

    float bi[8];
    #pragma unroll
    for (int j = 0; j < 8; ++j) bi[j] = bias[n0 + tx * 8 + j];

    #pragma unroll
    for (int i = 0; i < 8; ++i) {
        const int mrow = m0 + ty * 8 + i;
        const int b_ = mrow >> 11;             // / 2048
        const int t  = mrow & 2047;
        #pragma unroll
        for (int jj = 0; jj < 8; jj += 4) {
            const int n  = n0 + tx * 8 + jj;
            const int cc = n - which * CC;     // 0..767
            const int h  = cc >> 6;
            const int d  = cc & 63;
            float4 val;
            val.x = acc[i][jj + 0] + bi[jj + 0];
            val.y = acc[i][jj + 1] + bi[jj + 1];
            val.z = acc[i][jj + 2] + bi[jj + 2];
            val.w = acc[i][jj + 3] + bi[jj + 3];
            *(float4*)(dst + (((size_t)(b_ * HH + h) * TT + t) << 6) + d) = val;
        }
    }
}

// ---------------------------------------------------------------------------
// GEMM 2: out = att @ Wproj + bproj.   A [4096 x 768], B [768 x 768].
// ---------------------------------------------------------------------------
__global__ __launch_bounds__(256)
void athena_gemm_proj(const float* __restrict__ A, const float* __restrict__ W,
                      const float* __restrict__ bias, float* __restrict__ out)
{
    const int K = CC;   // 768
    const int N = CC;   // 768

    __shared__ float As[8][132];
    __shared__ float Bs[8][132];

    const int tid = threadIdx.x;
    const int m0 = blockIdx.y * 128;
    const int n0 = blockIdx.x * 128;

    const int tx = tid & 15;
    const int ty = tid >> 4;

    const int ar = tid >> 1;
    const int ac = (tid & 1) * 4;
    const int br = tid >> 5;
    const int bc = (tid & 31) * 4;

    const float* Aptr = A + (size_t)(m0 + ar) * K + ac;
    const float* Bptr = W + (size_t)br * N + n0 + bc;

    float acc[8][8];
    #pragma unroll
    for (int i = 0; i < 8; ++i)
        #pragma unroll
        for (int j = 0; j < 8; ++j) acc[i][j] = 0.f;

    for (int k0 = 0; k0 < K; k0 += 8) {
        float4 av = *(const float4*)(Aptr + k0);
        float4 bv = *(const float4*)(Bptr + (size_t)k0 * N);
        __syncthreads();
        As[ac + 0][ar] = av.x;
        As[ac + 1][ar] = av.y;
        As[ac + 2][ar] = av.z;
        As[ac + 3][ar] = av.w;
        *(float4*)&Bs[br][bc] = bv;
        __syncthreads();
        #pragma unroll
        for (int kk = 0; kk < 8; ++kk) {
            float a[8], b[8];
            *(float4*)&a[0] = *(const float4*)&As[kk][ty * 8];
            *(float4*)&a[4] = *(const float4*)&As[kk][ty * 8 + 4];
            *(float4*)&b[0] = *(const float4*)&Bs[kk][tx * 8];
            *(float4*)&b[4] = *(const float4*)&Bs[kk][tx * 8 + 4];
            #pragma unroll
            for (int i = 0; i < 8; ++i)
                #pragma unroll
                for (int j = 0; j < 8; ++j)
                    acc[i][j] += a[i] * b[j];
        }
    }

    float bi[8];
    #pragma unroll
    for (int j = 0; j < 8; ++j) bi[j] = bias[n0 + tx * 8 + j];

    #pragma unroll
    for (int i = 0; i < 8; ++i) {
        const int mrow = m0 + ty * 8 + i;
        #pragma unroll
        for (int jj = 0; jj < 8; jj += 4) {
            const int n = n0 + tx * 8 + jj;
            float4 val;
            val.x = acc[i][jj + 0] + bi[jj + 0];
            val.y = acc[i][jj + 1] + bi[jj + 1];
            val.z = acc[i][jj + 2] + bi[jj + 2];
            val.w = acc[i][jj + 3] + bi[jj + 3];
            *(float4*)(out + (size_t)mrow * N + n) = val;
        }
    }
}

// ---------------------------------------------------------------------------
// Flash attention (fp32, causal). One block = one (b,h, 64-query tile).
// 256 threads = 4 waves. Each row handled by 4 lanes (quad). Q row in regs.
// ---------------------------------------------------------------------------
__global__ __launch_bounds__(256)
void athena_attn(const float* __restrict__ q, const float* __restrict__ k,
                 const float* __restrict__ v, float* __restrict__ out)
{
    __shared__ float Ks[64][68];
    __shared__ float Vs[64][68];
    __shared__ float Ps[64][68];   // staging for Q, then P tile

    const int tid  = threadIdx.x;
    const int qt   = blockIdx.x & 31;   // query tile 0..31
    const int bh   = blockIdx.x >> 5;   // 0..23
    const int lane = tid & 63;
    const int wv   = tid >> 6;
    const int row  = wv * 16 + (lane >> 2);   // 0..63
    const int quad = lane & 3;

    const float* qbase = q + ((size_t)bh * TT + qt * 64) * 64;
    const float* kbase = k + (size_t)bh * TT * 64;
    const float* vbase = v + (size_t)bh * TT * 64;

    // ---- stage Q tile through LDS (coalesced), preload own row to regs ----
    {
        const int r  = tid >> 2;
        const int d0 = (tid & 3) * 16;
        const float* src = qbase + r * 64 + d0;
        #pragma unroll
        for (int i = 0; i < 4; ++i)
            *(float4*)&Ps[r][d0 + 4 * i] = *(const float4*)(src + 4 * i);
    }
    __syncthreads();
    float qreg[64];
    #pragma unroll
    for (int i = 0; i < 16; ++i)
        *(float4*)&qreg[4 * i] = *(const float4*)&Ps[row][4 * i];
    #pragma unroll
    for (int i = 0; i < 64; ++i) qreg[i] *= 0.125f;   // 1/sqrt(64)

    float m = -1e30f, l = 0.f;
    float o[16];
    #pragma unroll
    for (int i = 0; i < 16; ++i) o[i] = 0.f;

    for (int j = 0; j <= qt; ++j) {
        __syncthreads();   // also separates the Q preload reads from P writes
        {
            const int r  = tid >> 2;
            const int d0 = (tid & 3) * 16;
            const float* ks = kbase + ((size_t)(j * 64 + r) << 6) + d0;
            const float* vs = vbase + ((size_t)(j * 64 + r) << 6) + d0;
            #pragma unroll
            for (int i = 0; i < 4; ++i) {
                *(float4*)&Ks[r][d0 + 4 * i] = *(const float4*)(ks + 4 * i);
                *(float4*)&Vs[r][d0 + 4 * i] = *(const float4*)(vs + 4 * i);
            }
        }
        __syncthreads();

        // scores: this lane owns cols c = 4*i + quad
        float s[16];
        #pragma unroll
        for (int i = 0; i < 16; ++i) {
            const int c = 4 * i + quad;
            float a = 0.f;
            #pragma unroll
            for (int dd = 0; dd < 16; ++dd) {
                const float4 kv = *(const float4*)&Ks[c][4 * dd];
                a += qreg[4 * dd + 0] * kv.x + qreg[4 * dd + 1] * kv.y
                   + qreg[4 * dd + 2] * kv.z + qreg[4 * dd + 3] * kv.w;
            }
            s[i] = a;
        }
        if (j == qt) {   // causal mask, diagonal tile only
            #pragma unroll
            for (int i = 0; i < 16; ++i)
                if (4 * i + quad > row) s[i] = -1e30f;
        }

        // online softmax (row = 4-lane group)
        float tmax = s[0];
        #pragma unroll
        for (int i = 1; i < 16; ++i) tmax = fmaxf(tmax, s[i]);
        tmax = fmaxf(tmax, __shfl_xor(tmax, 1));
        tmax = fmaxf(tmax, __shfl_xor(tmax, 2));
        const float mnew = fmaxf(m, tmax);
        const float corr = __expf(m - mnew);
        float psum = 0.f;
        #pragma unroll
        for (int i = 0; i < 16; ++i) {
            const float p = __expf(s[i] - mnew);
            s[i] = p;
            psum += p;
        }
        psum += __shfl_xor(psum, 1);
        psum += __shfl_xor(psum, 2);
        l = l * corr + psum;
        m = mnew;
        #pragma unroll
        for (int i = 0; i < 16; ++i) o[i] *= corr;

        // publish P (wave-local round trip; same-wave DS ordering suffices)
        #pragma unroll
        for (int i = 0; i < 16; ++i) Ps[row][4 * i + quad] = s[i];

        // O += P @ V   (this lane owns dims d = quad*16 + [0..15])
        #pragma unroll
        for (int c = 0; c < 64; ++c) {
            const float p = Ps[row][c];
            #pragma unroll
            for (int i = 0; i < 4; ++i) {
                const float4 vv = *(const float4*)&Vs[c][quad * 16 + 4 * i];
                o[4 * i + 0] += p * vv.x;
                o[4 * i + 1] += p * vv.y;
                o[4 * i + 2] += p * vv.z;
                o[4 * i + 3] += p * vv.w;
            }
        }
    }

    // epilogue: normalize, write att output in [B, T, C] layout
    const float invl = 1.f / l;
    const int b_ = bh / HH;
    const int h  = bh % HH;
    float* op = out + ((size_t)b_ * TT + qt * 64 + row) * CC + h * 64 + quad * 16;
    #pragma unroll
    for (int i = 0; i < 4; ++i) {
        float4 vv;
        vv.x = o[4 * i + 0] * invl;
        vv.y = o[4 * i + 1] * invl;
        vv.z = o[4 * i + 2] * invl;
        vv.w = o[4 * i + 3] * invl;
        *(float4*)(op + 4 * i) = vv;
    }
}

// ---------------------------------------------------------------------------
extern "C" void kernel_launch(void* const* d_in, const int* in_sizes, int n_in,
                              void* d_out, int out_size, void* d_ws, size_t ws_size,
                              hipStream_t stream)
{
    const float* x     = (const float*)d_in[0];
    const float* Wqkv  = (const float*)d_in[1];
    const float* bqkv  = (const float*)d_in[2];
    const float* Wproj = (const float*)d_in[3];
    const float* bproj = (const float*)d_in[4];
    float* out = (float*)d_out;

    const size_t per = (size_t)BB * HH * TT * HD;   // 3,145,728 floats
    float* qbuf = (float*)d_ws;
    float* kbuf = qbuf + per;
    float* vbuf = kbuf + per;
    float* att  = vbuf + per;                       // [B*T, C]

    athena_gemm_qkv<<<dim3(N3 / 128, (BB * TT) / 128), 256, 0, stream>>>(
        x, Wqkv, bqkv, qbuf, kbuf, vbuf);
    athena_attn<<<dim3(BB * HH * 32), 256, 0, stream>>>(qbuf, kbuf, vbuf, att);
    athena_gemm_proj<<<dim3(CC / 128, (BB * TT) / 128), 256, 0, stream>>>(
        att, Wproj, bproj, out);
}

// Round 2
// 448.154 us; speedup vs baseline: 3.2443x; 3.2443x over previous
//
#include <hip/hip_runtime.h>
#include <math.h>

#define BB 2
#define TT 2048
#define CC 768
#define HH 12
#define HD 64
#define N3 (3*CC)

typedef __attribute__((ext_vector_type(8))) short short8;
typedef __attribute__((ext_vector_type(4))) float f32x4;

static __device__ __forceinline__ unsigned short f2bf(float x) {
    union { float f; unsigned u; } v; v.f = x;
    unsigned r = v.u + 0x7fffu + ((v.u >> 16) & 1u);   // RNE
    return (unsigned short)(r >> 16);
}
static __device__ __forceinline__ float bf2f(unsigned short h) {
    union { unsigned u; float f; } v; v.u = ((unsigned)h) << 16; return v.f;
}
static __device__ __forceinline__ void split_bf(float x, unsigned short& hi, unsigned short& lo) {
    hi = f2bf(x);
    lo = f2bf(x - bf2f(hi));     // exact residual (Sterbenz), next 8 mantissa bits
}

// ---------------------------------------------------------------------------
// Split-bf16 3-pass MFMA GEMM: C = A[4096xK=768] * W[768xNCOLS] + bias.
// 128x128 tile, BK=32, 4 waves (2x2), wave = 64x64 (4x4 frags of 16x16x32).
// MODE 0: scatter to q/k/v [B*H][T][64].  MODE 1: plain row-major out.
// ---------------------------------------------------------------------------
template<int NCOLS, int MODE>
__global__ __launch_bounds__(256, 2)
void mm_split(const float* __restrict__ A, const float* __restrict__ W,
              const float* __restrict__ bias,
              float* __restrict__ o0, float* __restrict__ o1, float* __restrict__ o2)
{
    __shared__ unsigned short Ah[128][40], Al[128][40];   // [m][k], pad->free
    __shared__ unsigned short Bh[128][40], Bl[128][40];   // [n][k] (transposed)

    const int tid = threadIdx.x;
    const int m0 = blockIdx.y * 128, n0 = blockIdx.x * 128;
    const int lane = tid & 63, wv = tid >> 6;
    const int wm = wv >> 1, wn = wv & 1;
    const int r16 = lane & 15, kg = lane >> 4;

    f32x4 acc[4][4];
    #pragma unroll
    for (int i = 0; i < 4; ++i)
        #pragma unroll
        for (int j = 0; j < 4; ++j) acc[i][j] = (f32x4)0.f;

    for (int k0 = 0; k0 < 768; k0 += 32) {
        float4 av[4], bv[4];
        int arow[4], akq[4], bkr[4], bnq[4];
        #pragma unroll
        for (int i = 0; i < 4; ++i) {
            const int fid = tid + i * 256;
            arow[i] = fid >> 3;  akq[i] = fid & 7;     // A: 128 rows x 8 float4
            bkr[i]  = fid >> 5;  bnq[i] = fid & 31;    // B: 32 k x 32 float4
            av[i] = *(const float4*)(A + (size_t)(m0 + arow[i]) * 768 + k0 + akq[i] * 4);
            bv[i] = *(const float4*)(W + (size_t)(k0 + bkr[i]) * NCOLS + n0 + bnq[i] * 4);
        }
        __syncthreads();
        #pragma unroll
        for (int i = 0; i < 4; ++i) {
            const float* p = (const float*)&av[i];
            unsigned short h[4], l[4];
            #pragma unroll
            for (int e = 0; e < 4; ++e) split_bf(p[e], h[e], l[e]);
            *(unsigned*)&Ah[arow[i]][akq[i] * 4]     = (unsigned)h[0] | ((unsigned)h[1] << 16);
            *(unsigned*)&Ah[arow[i]][akq[i] * 4 + 2] = (unsigned)h[2] | ((unsigned)h[3] << 16);
            *(unsigned*)&Al[arow[i]][akq[i] * 4]     = (unsigned)l[0] | ((unsigned)l[1] << 16);
            *(unsigned*)&Al[arow[i]][akq[i] * 4 + 2] = (unsigned)l[2] | ((unsigned)l[3] << 16);
            const float* pb = (const float*)&bv[i];
            #pragma unroll
            for (int e = 0; e < 4; ++e) {
                unsigned short hb, lb; split_bf(pb[e], hb, lb);
                Bh[bnq[i] * 4 + e][bkr[i]] = hb;
                Bl[bnq[i] * 4 + e][bkr[i]] = lb;
            }
        }
        __syncthreads();

        short8 ah[4], alo[4], bh[4], blo[4];
        #pragma unroll
        for (int t = 0; t < 4; ++t) {
            ah[t]  = *(const short8*)&Ah[wm * 64 + t * 16 + r16][kg * 8];
            alo[t] = *(const short8*)&Al[wm * 64 + t * 16 + r16][kg * 8];
            bh[t]  = *(const short8*)&Bh[wn * 64 + t * 16 + r16][kg * 8];
            blo[t] = *(const short8*)&Bl[wn * 64 + t * 16 + r16][kg * 8];
        }
        #pragma unroll
        for (int mt = 0; mt < 4; ++mt)
            #pragma unroll
            for (int nt = 0; nt < 4; ++nt) {
                acc[mt][nt] = __builtin_amdgcn_mfma_f32_16x16x32_bf16(ah[mt],  bh[nt],  acc[mt][nt], 0, 0, 0);
                acc[mt][nt] = __builtin_amdgcn_mfma_f32_16x16x32_bf16(ah[mt],  blo[nt], acc[mt][nt], 0, 0, 0);
                acc[mt][nt] = __builtin_amdgcn_mfma_f32_16x16x32_bf16(alo[mt], bh[nt],  acc[mt][nt], 0, 0, 0);
            }
    }

    float bi[4];
    #pragma unroll
    for (int nt = 0; nt < 4; ++nt) bi[nt] = bias[n0 + wn * 64 + nt * 16 + r16];

    const int which = n0 / CC;
    float* dst = (MODE == 0) ? ((which == 0) ? o0 : (which == 1 ? o1 : o2)) : o0;

    #pragma unroll
    for (int mt = 0; mt < 4; ++mt)
        #pragma unroll
        for (int nt = 0; nt < 4; ++nt)
            #pragma unroll
            for (int r = 0; r < 4; ++r) {
                const int grow = m0 + wm * 64 + mt * 16 + kg * 4 + r;
                const int gcol = n0 + wn * 64 + nt * 16 + r16;
                const float val = acc[mt][nt][r] + bi[nt];
                if (MODE == 0) {
                    const int cc = gcol - which * CC;
                    const int h = cc >> 6, d = cc & 63;
                    const int b_ = grow >> 11, t = grow & 2047;
                    dst[(((size_t)(b_ * HH + h) * TT + t) << 6) + d] = val;
                } else {
                    dst[(size_t)grow * CC + gcol] = val;
                }
            }
}

// ---------------------------------------------------------------------------
// Flash attention, MFMA. Block = (bh, 64-row q-tile), 4 waves x 16 rows.
// QK^T: 3-pass split-bf16.  PV: bf16(P) x (Vhi,Vlo) 2-pass.
// qt descending across blockIdx for load balance.
// ---------------------------------------------------------------------------
__global__ __launch_bounds__(256)
void attn_mfma(const float* __restrict__ q, const float* __restrict__ k,
               const float* __restrict__ v, float* __restrict__ out)
{
    __shared__ unsigned short Kh[64][72], Kl[64][72];   // [key][d]
    __shared__ unsigned short Vh[64][72], Vl[64][72];   // [d][key] (transposed)
    __shared__ unsigned short Ps[4][16][72];            // per-wave P tile [row][key]

    const int tid = threadIdx.x;
    const int bid = blockIdx.x;
    const int qt = 31 - (bid / 24);     // long blocks first
    const int bh = bid % 24;
    const int lane = tid & 63, wv = tid >> 6;
    const int r16 = lane & 15, kg = lane >> 4;

    // Q fragments direct from global (row = lane&15, d = kg*8+j per 32-k step)
    const float* qrow = q + ((size_t)bh * TT + qt * 64 + wv * 16 + r16) * 64;
    short8 qh[2], ql[2];
    #pragma unroll
    for (int ks = 0; ks < 2; ++ks) {
        float tmp[8];
        *(float4*)&tmp[0] = *(const float4*)(qrow + ks * 32 + kg * 8);
        *(float4*)&tmp[4] = *(const float4*)(qrow + ks * 32 + kg * 8 + 4);
        #pragma unroll
        for (int j = 0; j < 8; ++j) {
            unsigned short h, l; split_bf(tmp[j] * 0.125f, h, l);
            qh[ks][j] = (short)h; ql[ks][j] = (short)l;
        }
    }

    f32x4 o_acc[4];
    #pragma unroll
    for (int i = 0; i < 4; ++i) o_acc[i] = (f32x4)0.f;
    float m_s[4] = {-1e30f, -1e30f, -1e30f, -1e30f};
    float l_s[4] = {0.f, 0.f, 0.f, 0.f};

    const float* kbase = k + (size_t)bh * TT * 64;
    const float* vbase = v + (size_t)bh * TT * 64;

    for (int j = 0; j <= qt; ++j) {
        float4 kv[4], vv[4];
        int key_[4], dq_[4];
        #pragma unroll
        for (int i = 0; i < 4; ++i) {
            const int fid = tid + i * 256;
            key_[i] = fid >> 4; dq_[i] = fid & 15;
            kv[i] = *(const float4*)(kbase + ((size_t)(j * 64 + key_[i]) << 6) + dq_[i] * 4);
            vv[i] = *(const float4*)(vbase + ((size_t)(j * 64 + key_[i]) << 6) + dq_[i] * 4);
        }
        __syncthreads();
        #pragma unroll
        for (int i = 0; i < 4; ++i) {
            const float* p = (const float*)&kv[i];
            unsigned short h[4], l[4];
            #pragma unroll
            for (int e = 0; e < 4; ++e) split_bf(p[e], h[e], l[e]);
            *(unsigned*)&Kh[key_[i]][dq_[i] * 4]     = (unsigned)h[0] | ((unsigned)h[1] << 16);
            *(unsigned*)&Kh[key_[i]][dq_[i] * 4 + 2] = (unsigned)h[2] | ((unsigned)h[3] << 16);
            *(unsigned*)&Kl[key_[i]][dq_[i] * 4]     = (unsigned)l[0] | ((unsigned)l[1] << 16);
            *(unsigned*)&Kl[key_[i]][dq_[i] * 4 + 2] = (unsigned)l[2] | ((unsigned)l[3] << 16);
            const float* pv = (const float*)&vv[i];
            #pragma unroll
            for (int e = 0; e < 4; ++e) {
                unsigned short hb, lb; split_bf(pv[e], hb, lb);
                Vh[dq_[i] * 4 + e][key_[i]] = hb;
                Vl[dq_[i] * 4 + e][key_[i]] = lb;
            }
        }
        __syncthreads();

        // --- scores S = (Q*scale) @ K^T, 3-pass split ---
        f32x4 s[4];
        #pragma unroll
        for (int nt = 0; nt < 4; ++nt) s[nt] = (f32x4)0.f;
        #pragma unroll
        for (int ks = 0; ks < 2; ++ks)
            #pragma unroll
            for (int nt = 0; nt < 4; ++nt) {
                short8 khf = *(const short8*)&Kh[nt * 16 + r16][ks * 32 + kg * 8];
                short8 klf = *(const short8*)&Kl[nt * 16 + r16][ks * 32 + kg * 8];
                s[nt] = __builtin_amdgcn_mfma_f32_16x16x32_bf16(qh[ks], khf, s[nt], 0, 0, 0);
                s[nt] = __builtin_amdgcn_mfma_f32_16x16x32_bf16(qh[ks], klf, s[nt], 0, 0, 0);
                s[nt] = __builtin_amdgcn_mfma_f32_16x16x32_bf16(ql[ks], khf, s[nt], 0, 0, 0);
            }

        if (j == qt) {   // causal mask on diagonal tile
            #pragma unroll
            for (int nt = 0; nt < 4; ++nt)
                #pragma unroll
                for (int r = 0; r < 4; ++r)
                    if (nt * 16 + r16 > wv * 16 + kg * 4 + r) s[nt][r] = -1e30f;
        }

        // --- online softmax (row r lives in a 16-lane group) ---
        #pragma unroll
        for (int r = 0; r < 4; ++r) {
            float mx = fmaxf(fmaxf(s[0][r], s[1][r]), fmaxf(s[2][r], s[3][r]));
            mx = fmaxf(mx, __shfl_xor(mx, 1));
            mx = fmaxf(mx, __shfl_xor(mx, 2));
            mx = fmaxf(mx, __shfl_xor(mx, 4));
            mx = fmaxf(mx, __shfl_xor(mx, 8));
            const float mn = fmaxf(m_s[r], mx);
            const float corr = __expf(m_s[r] - mn);
            float ps = 0.f;
            #pragma unroll
            for (int nt = 0; nt < 4; ++nt) {
                const float p = __expf(s[nt][r] - mn);
                s[nt][r] = p;
                ps += p;
            }
            ps += __shfl_xor(ps, 1);
            ps += __shfl_xor(ps, 2);
            ps += __shfl_xor(ps, 4);
            ps += __shfl_xor(ps, 8);
            l_s[r] = l_s[r] * corr + ps;
            m_s[r] = mn;
            #pragma unroll
            for (int nt = 0; nt < 4; ++nt) o_acc[nt][r] *= corr;
        }

        // --- P -> bf16 via wave-local LDS round-trip ---
        #pragma unroll
        for (int nt = 0; nt < 4; ++nt)
            #pragma unroll
            for (int r = 0; r < 4; ++r)
                Ps[wv][kg * 4 + r][nt * 16 + r16] = f2bf(s[nt][r]);

        // --- O += P @ V (2-pass over Vhi/Vlo) ---
        #pragma unroll
        for (int ks = 0; ks < 2; ++ks) {
            short8 pa = *(const short8*)&Ps[wv][r16][ks * 32 + kg * 8];
            #pragma unroll
            for (int nt = 0; nt < 4; ++nt) {
                short8 vhf = *(const short8*)&Vh[nt * 16 + r16][ks * 32 + kg * 8];
                short8 vlf = *(const short8*)&Vl[nt * 16 + r16][ks * 32 + kg * 8];
                o_acc[nt] = __builtin_amdgcn_mfma_f32_16x16x32_bf16(pa, vhf, o_acc[nt], 0, 0, 0);
                o_acc[nt] = __builtin_amdgcn_mfma_f32_16x16x32_bf16(pa, vlf, o_acc[nt], 0, 0, 0);
            }
        }
    }

    // epilogue: normalize + write [B,T,C]
    const int b_ = bh / HH, h = bh % HH;
    #pragma unroll
    for (int r = 0; r < 4; ++r) {
        const float inv = 1.f / l_s[r];
        const int t = qt * 64 + wv * 16 + kg * 4 + r;
        float* op = out + ((size_t)b_ * TT + t) * CC + h * 64;
        #pragma unroll
        for (int nt = 0; nt < 4; ++nt)
            op[nt * 16 + r16] = o_acc[nt][r] * inv;
    }
}

// ---------------------------------------------------------------------------
extern "C" void kernel_launch(void* const* d_in, const int* in_sizes, int n_in,
                              void* d_out, int out_size, void* d_ws, size_t ws_size,
                              hipStream_t stream)
{
    const float* x     = (const float*)d_in[0];
    const float* Wqkv  = (const float*)d_in[1];
    const float* bqkv  = (const float*)d_in[2];
    const float* Wproj = (const float*)d_in[3];
    const float* bproj = (const float*)d_in[4];
    float* out = (float*)d_out;

    const size_t per = (size_t)BB * HH * TT * HD;
    float* qbuf = (float*)d_ws;
    float* kbuf = qbuf + per;
    float* vbuf = kbuf + per;
    float* att  = vbuf + per;   // [B*T, C]

    mm_split<N3, 0><<<dim3(N3 / 128, (BB * TT) / 128), 256, 0, stream>>>(
        x, Wqkv, bqkv, qbuf, kbuf, vbuf);
    attn_mfma<<<dim3(BB * HH * 32), 256, 0, stream>>>(qbuf, kbuf, vbuf, att);
    mm_split<CC, 1><<<dim3(CC / 128, (BB * TT) / 128), 256, 0, stream>>>(
        att, Wproj, bproj, out, nullptr, nullptr);
}

// Round 4
// 264.744 us; speedup vs baseline: 5.4918x; 1.6928x over previous
//
#include <hip/hip_runtime.h>
#include <math.h>

#define BB 2
#define TT 2048
#define CC 768
#define HH 12
#define HD 64
#define N3 (3*CC)

typedef __attribute__((ext_vector_type(8))) short short8;
typedef __attribute__((ext_vector_type(4))) float f32x4;
typedef unsigned short u16;

static __device__ __forceinline__ u16 f2bf(float x) {
    union { float f; unsigned u; } v; v.f = x;
    unsigned r = v.u + 0x7fffu + ((v.u >> 16) & 1u);   // RNE
    return (u16)(r >> 16);
}
static __device__ __forceinline__ float bf2f(u16 h) {
    union { unsigned u; float f; } v; v.u = ((unsigned)h) << 16; return v.f;
}
static __device__ __forceinline__ void split_bf(float x, u16& hi, u16& lo) {
    hi = f2bf(x);
    lo = f2bf(x - bf2f(hi));     // exact residual, next 8 mantissa bits
}

// global -> LDS direct copy, 16B per lane. LDS dest = base + lane*16 (wave
// uniform base); global src is per-lane.
static __device__ __forceinline__ void gl16(const void* g, void* l) {
    __builtin_amdgcn_global_load_lds(
        (const __attribute__((address_space(1))) void*)g,
        (__attribute__((address_space(3))) void*)l, 16, 0, 0);
}

// ---------------------------------------------------------------------------
// convert: fp32 row-major -> split bf16 planes (same layout). One float4/thread.
// ---------------------------------------------------------------------------
__global__ __launch_bounds__(256)
void conv_split(const float* __restrict__ src, u16* __restrict__ h, u16* __restrict__ l)
{
    const int i = blockIdx.x * 256 + threadIdx.x;
    float4 v = ((const float4*)src)[i];
    ushort4 hv, lv;
    split_bf(v.x, hv.x, lv.x); split_bf(v.y, hv.y, lv.y);
    split_bf(v.z, hv.z, lv.z); split_bf(v.w, hv.w, lv.w);
    ((ushort4*)h)[i] = hv;
    ((ushort4*)l)[i] = lv;
}

// ---------------------------------------------------------------------------
// convert + transpose: W[768][N] fp32 -> Th/Tl [N][768] split bf16.
// 64x64 tiles, 256 threads.
// ---------------------------------------------------------------------------
__global__ __launch_bounds__(256)
void conv_tsplit(const float* __restrict__ W, u16* __restrict__ Th, u16* __restrict__ Tl, int N)
{
    __shared__ float Tt[64][65];
    const int tid = threadIdx.x;
    const int n0 = blockIdx.x * 64, k0 = blockIdx.y * 64;
    {
        const int r = tid >> 2, q = tid & 3;
        #pragma unroll
        for (int i = 0; i < 4; ++i) {
            float4 v = *(const float4*)(W + (size_t)(k0 + r) * N + n0 + q * 16 + i * 4);
            Tt[q * 16 + i * 4 + 0][r] = v.x;
            Tt[q * 16 + i * 4 + 1][r] = v.y;
            Tt[q * 16 + i * 4 + 2][r] = v.z;
            Tt[q * 16 + i * 4 + 3][r] = v.w;
        }
    }
    __syncthreads();
    {
        const int n = tid >> 2, q = tid & 3;
        u16 hh[16], ll[16];
        #pragma unroll
        for (int j = 0; j < 16; ++j) split_bf(Tt[n][q * 16 + j], hh[j], ll[j]);
        u16* dh = Th + (size_t)(n0 + n) * 768 + k0 + q * 16;
        u16* dl = Tl + (size_t)(n0 + n) * 768 + k0 + q * 16;
        *(short8*)(dh) = *(short8*)&hh[0];  *(short8*)(dh + 8) = *(short8*)&hh[8];
        *(short8*)(dl) = *(short8*)&ll[0];  *(short8*)(dl + 8) = *(short8*)&ll[8];
    }
}

// ---------------------------------------------------------------------------
// Split-bf16 3-pass MFMA GEMM, m97-style staging.
// A planes [4096][768] bf16 (hi,lo). B planes [NCOLS][768] (pre-transposed).
// 128x128 tile, BK=32, 4 waves (2x2), global_load_lds w/ source-swizzle.
// MODE 0: epilogue -> split q/k/v (+bias). MODE 1: fp32 out (+bias).
// ---------------------------------------------------------------------------
template<int NCOLS, int MODE>
__global__ __launch_bounds__(256)
void mm3(const u16* __restrict__ Ah_g, const u16* __restrict__ Al_g,
         const u16* __restrict__ Bh_g, const u16* __restrict__ Bl_g,
         const float* __restrict__ bias, float* __restrict__ outF,
         u16* __restrict__ qh, u16* __restrict__ ql,
         u16* __restrict__ kh, u16* __restrict__ kl,
         u16* __restrict__ vth, u16* __restrict__ vtl)
{
    __shared__ u16 gsm[16384];           // Ah@0 Al@8192 Bh@16384 Bl@24576 (bytes)
    char* smb = (char*)gsm;
    const int tid = threadIdx.x, lane = tid & 63, wv = tid >> 6;
    const int wm = wv >> 1, wn = wv & 1, r16 = lane & 15, kg = lane >> 4;
    const int m0 = blockIdx.y * 128, n0 = blockIdx.x * 128;

    // staging: per-lane global pointers (source chunk-swizzled), uniform LDS base
    const u16 *pAh[2], *pAl[2], *pBh[2], *pBl[2];
    int ldsq[2];
    #pragma unroll
    for (int qq = 0; qq < 2; ++qq) {
        const int L = wv * 2048 + qq * 1024 + lane * 16;
        const int row = L >> 6, c = (L >> 4) & 3;
        const int cp = c ^ ((row >> 1) & 3);
        ldsq[qq] = wv * 2048 + qq * 1024;
        const size_t aoff = (size_t)(m0 + row) * 768 + cp * 8;
        const size_t boff = (size_t)(n0 + row) * 768 + cp * 8;
        pAh[qq] = Ah_g + aoff; pAl[qq] = Al_g + aoff;
        pBh[qq] = Bh_g + boff; pBl[qq] = Bl_g + boff;
    }

    // fragment ds_read byte addrs (plane-relative, swizzled)
    int aA[4], aB[4];
    #pragma unroll
    for (int t = 0; t < 4; ++t) {
        const int rA = wm * 64 + t * 16 + r16;
        const int rB = wn * 64 + t * 16 + r16;
        aA[t] = rA * 64 + ((kg ^ ((rA >> 1) & 3)) << 4);
        aB[t] = rB * 64 + ((kg ^ ((rB >> 1) & 3)) << 4);
    }

    f32x4 acc[4][4];
    #pragma unroll
    for (int i = 0; i < 4; ++i)
        #pragma unroll
        for (int j = 0; j < 4; ++j) acc[i][j] = (f32x4)0.f;

    for (int ks = 0; ks < 24; ++ks) {
        __syncthreads();
        #pragma unroll
        for (int qq = 0; qq < 2; ++qq) {
            gl16(pAh[qq], smb + ldsq[qq]);
            gl16(pAl[qq], smb + 8192 + ldsq[qq]);
            gl16(pBh[qq], smb + 16384 + ldsq[qq]);
            gl16(pBl[qq], smb + 24576 + ldsq[qq]);
            pAh[qq] += 32; pAl[qq] += 32; pBh[qq] += 32; pBl[qq] += 32;
        }
        __syncthreads();

        short8 ah[4], al[4], bh[4], bl[4];
        #pragma unroll
        for (int t = 0; t < 4; ++t) {
            ah[t] = *(const short8*)(smb + aA[t]);
            al[t] = *(const short8*)(smb + 8192 + aA[t]);
            bh[t] = *(const short8*)(smb + 16384 + aB[t]);
            bl[t] = *(const short8*)(smb + 24576 + aB[t]);
        }
        #pragma unroll
        for (int mt = 0; mt < 4; ++mt)
            #pragma unroll
            for (int nt = 0; nt < 4; ++nt) {
                acc[mt][nt] = __builtin_amdgcn_mfma_f32_16x16x32_bf16(ah[mt], bh[nt], acc[mt][nt], 0, 0, 0);
                acc[mt][nt] = __builtin_amdgcn_mfma_f32_16x16x32_bf16(ah[mt], bl[nt], acc[mt][nt], 0, 0, 0);
                acc[mt][nt] = __builtin_amdgcn_mfma_f32_16x16x32_bf16(al[mt], bh[nt], acc[mt][nt], 0, 0, 0);
            }
    }

    float bi[4];
    #pragma unroll
    for (int nt = 0; nt < 4; ++nt) bi[nt] = bias[n0 + wn * 64 + nt * 16 + r16];

    if (MODE == 1) {
        #pragma unroll
        for (int mt = 0; mt < 4; ++mt)
            #pragma unroll
            for (int nt = 0; nt < 4; ++nt)
                #pragma unroll
                for (int r = 0; r < 4; ++r) {
                    const int grow = m0 + wm * 64 + mt * 16 + kg * 4 + r;
                    const int gcol = n0 + wn * 64 + nt * 16 + r16;
                    outF[(size_t)grow * CC + gcol] = acc[mt][nt][r] + bi[nt];
                }
    } else {
        const int which = n0 / CC;       // uniform per block
        const int b_ = m0 >> 11;
        #pragma unroll
        for (int mt = 0; mt < 4; ++mt) {
            const int tb = ((m0 & 2047) + wm * 64 + mt * 16 + kg * 4);
            #pragma unroll
            for (int nt = 0; nt < 4; ++nt) {
                const int gcol = n0 + wn * 64 + nt * 16 + r16;
                const int cc = gcol - which * CC;
                const int h = cc >> 6, d = cc & 63;
                const int bh_ = b_ * HH + h;
                if (which == 2) {
                    ushort4 hv, lv;
                    #pragma unroll
                    for (int r = 0; r < 4; ++r) {
                        u16 hi, lo; split_bf(acc[mt][nt][r] + bi[nt], hi, lo);
                        ((u16*)&hv)[r] = hi; ((u16*)&lv)[r] = lo;
                    }
                    const size_t idx = ((size_t)bh_ * 64 + d) * 2048 + tb;
                    *(ushort4*)(vth + idx) = hv;
                    *(ushort4*)(vtl + idx) = lv;
                } else {
                    u16* dh = (which == 0) ? qh : kh;
                    u16* dl = (which == 0) ? ql : kl;
                    #pragma unroll
                    for (int r = 0; r < 4; ++r) {
                        u16 hi, lo; split_bf(acc[mt][nt][r] + bi[nt], hi, lo);
                        const size_t idx = (((size_t)bh_ * 2048 + tb + r) << 6) + d;
                        dh[idx] = hi; dl[idx] = lo;
                    }
                }
            }
        }
    }
}

// ---------------------------------------------------------------------------
// Flash attention, split-bf16 MFMA, preconverted inputs.
// Block = (bh, 64-row q-tile), 4 waves x 16 q-rows. K [key][d], V^T [d][key]
// staged via global_load_lds with source chunk-swizzle; epilogue emits split
// att planes for the proj GEMM.
// ---------------------------------------------------------------------------
__global__ __launch_bounds__(256)
void attn3(const u16* __restrict__ qh, const u16* __restrict__ ql,
           const u16* __restrict__ kh, const u16* __restrict__ kl,
           const u16* __restrict__ vth, const u16* __restrict__ vtl,
           u16* __restrict__ atth, u16* __restrict__ attl)
{
    __shared__ u16 smem[20480];   // Kh@0 Kl@8192 VTh@16384 VTl@24576 P@32768 (bytes)
    char* smb = (char*)smem;

    const int tid = threadIdx.x, bid = blockIdx.x;
    const int qt = 31 - (bid / 24);          // long q-tiles dispatch first
    const int bh = bid % 24;
    const int lane = tid & 63, wv = tid >> 6;
    const int r16 = lane & 15, kg = lane >> 4;

    // Q fragments straight from global split planes
    const size_t qro = ((size_t)bh * TT + qt * 64 + wv * 16 + r16) * 64;
    short8 qfh[2], qfl[2];
    #pragma unroll
    for (int ks = 0; ks < 2; ++ks) {
        qfh[ks] = *(const short8*)(qh + qro + ks * 32 + kg * 8);
        qfl[ks] = *(const short8*)(ql + qro + ks * 32 + kg * 8);
    }

    // staging pointers
    const u16 *pkh[2], *pkl[2], *pvh[2], *pvl[2];
    int ldsq[2];
    #pragma unroll
    for (int qq = 0; qq < 2; ++qq) {
        const int L = wv * 2048 + qq * 1024 + lane * 16;
        const int row = L >> 7, c = (L >> 4) & 7;
        const int cp = c ^ (row & 7);
        ldsq[qq] = wv * 2048 + qq * 1024;
        const size_t kof = ((size_t)bh * TT + row) * 64 + cp * 8;     // +4096/iter
        const size_t vof = ((size_t)bh * 64 + row) * TT + cp * 8;     // +64/iter
        pkh[qq] = kh + kof; pkl[qq] = kl + kof;
        pvh[qq] = vth + vof; pvl[qq] = vtl + vof;
    }

    // fragment ds_read byte addrs (plane-relative, swizzled); K and V^T share
    int aK[2][4], aP[2];
    #pragma unroll
    for (int ks = 0; ks < 2; ++ks) {
        #pragma unroll
        for (int nt = 0; nt < 4; ++nt) {
            const int row = nt * 16 + r16;
            aK[ks][nt] = row * 128 + (((ks * 4 + kg) ^ (row & 7)) << 4);
        }
        aP[ks] = 32768 + wv * 2048 + r16 * 128 + (((ks * 4 + kg) ^ (r16 & 7)) << 4);
    }
    int pwb[4], pwx[4];
    #pragma unroll
    for (int r = 0; r < 4; ++r) {
        const int prow = kg * 4 + r;
        pwb[r] = 32768 + wv * 2048 + prow * 128;
        pwx[r] = (prow & 7) << 3;
    }

    f32x4 o_acc[4];
    #pragma unroll
    for (int i = 0; i < 4; ++i) o_acc[i] = (f32x4)0.f;
    float m_s[4] = {-1e30f, -1e30f, -1e30f, -1e30f};
    float l_s[4] = {0.f, 0.f, 0.f, 0.f};

    for (int j = 0; j <= qt; ++j) {
        __syncthreads();
        #pragma unroll
        for (int qq = 0; qq < 2; ++qq) {
            gl16(pkh[qq], smb + ldsq[qq]);
            gl16(pkl[qq], smb + 8192 + ldsq[qq]);
            gl16(pvh[qq], smb + 16384 + ldsq[qq]);
            gl16(pvl[qq], smb + 24576 + ldsq[qq]);
            pkh[qq] += 4096; pkl[qq] += 4096; pvh[qq] += 64; pvl[qq] += 64;
        }
        __syncthreads();

        // S = Q K^T (3-pass), then *1/sqrt(64)
        f32x4 s[4];
        #pragma unroll
        for (int nt = 0; nt < 4; ++nt) s[nt] = (f32x4)0.f;
        #pragma unroll
        for (int ks = 0; ks < 2; ++ks)
            #pragma unroll
            for (int nt = 0; nt < 4; ++nt) {
                short8 khf = *(const short8*)(smb + aK[ks][nt]);
                short8 klf = *(const short8*)(smb + 8192 + aK[ks][nt]);
                s[nt] = __builtin_amdgcn_mfma_f32_16x16x32_bf16(qfh[ks], khf, s[nt], 0, 0, 0);
                s[nt] = __builtin_amdgcn_mfma_f32_16x16x32_bf16(qfh[ks], klf, s[nt], 0, 0, 0);
                s[nt] = __builtin_amdgcn_mfma_f32_16x16x32_bf16(qfl[ks], khf, s[nt], 0, 0, 0);
            }
        #pragma unroll
        for (int nt = 0; nt < 4; ++nt) s[nt] *= 0.125f;

        if (j == qt) {
            // causal mask: key-in-tile (nt*16+r16) vs query-in-tile (wv*16+kg*4+r)
            #pragma unroll
            for (int nt = 0; nt < 4; ++nt)
                #pragma unroll
                for (int r = 0; r < 4; ++r)
                    if (nt * 16 + r16 > wv * 16 + kg * 4 + r) s[nt][r] = -1e30f;
        }

        // online softmax (row lives in a 16-lane group)
        #pragma unroll
        for (int r = 0; r < 4; ++r) {
            float mx = fmaxf(fmaxf(s[0][r], s[1][r]), fmaxf(s[2][r], s[3][r]));
            mx = fmaxf(mx, __shfl_xor(mx, 1));
            mx = fmaxf(mx, __shfl_xor(mx, 2));
            mx = fmaxf(mx, __shfl_xor(mx, 4));
            mx = fmaxf(mx, __shfl_xor(mx, 8));
            const float mn = fmaxf(m_s[r], mx);
            const float corr = __expf(m_s[r] - mn);
            float ps = 0.f;
            #pragma unroll
            for (int nt = 0; nt < 4; ++nt) {
                const float p = __expf(s[nt][r] - mn);
                s[nt][r] = p;
                ps += p;
            }
            ps += __shfl_xor(ps, 1);
            ps += __shfl_xor(ps, 2);
            ps += __shfl_xor(ps, 4);
            ps += __shfl_xor(ps, 8);
            l_s[r] = l_s[r] * corr + ps;
            m_s[r] = mn;
            #pragma unroll
            for (int nt = 0; nt < 4; ++nt) o_acc[nt][r] *= corr;
        }

        // P -> bf16, swizzled wave-local LDS round trip
        #pragma unroll
        for (int nt = 0; nt < 4; ++nt)
            #pragma unroll
            for (int r = 0; r < 4; ++r)
                *(u16*)(smb + pwb[r] + (((nt * 16 + r16) ^ pwx[r]) << 1)) = f2bf(s[nt][r]);

        // O += P @ V (2-pass hi/lo)
        #pragma unroll
        for (int ks = 0; ks < 2; ++ks) {
            short8 pa = *(const short8*)(smb + aP[ks]);
            #pragma unroll
            for (int nt = 0; nt < 4; ++nt) {
                short8 vhf = *(const short8*)(smb + 16384 + aK[ks][nt]);
                short8 vlf = *(const short8*)(smb + 24576 + aK[ks][nt]);
                o_acc[nt] = __builtin_amdgcn_mfma_f32_16x16x32_bf16(pa, vhf, o_acc[nt], 0, 0, 0);
                o_acc[nt] = __builtin_amdgcn_mfma_f32_16x16x32_bf16(pa, vlf, o_acc[nt], 0, 0, 0);
            }
        }
    }

    // epilogue: normalize, split, write att planes [B*T][C]
    const int b_ = bh / HH, h = bh % HH;
    #pragma unroll
    for (int r = 0; r < 4; ++r) {
        const float inv = 1.f / l_s[r];
        const int t = qt * 64 + wv * 16 + kg * 4 + r;
        const size_t base = ((size_t)b_ * TT + t) * CC + h * 64;
        #pragma unroll
        for (int nt = 0; nt < 4; ++nt) {
            u16 hi, lo; split_bf(o_acc[nt][r] * inv, hi, lo);
            atth[base + nt * 16 + r16] = hi;
            attl[base + nt * 16 + r16] = lo;
        }
    }
}

// ---------------------------------------------------------------------------
extern "C" void kernel_launch(void* const* d_in, const int* in_sizes, int n_in,
                              void* d_out, int out_size, void* d_ws, size_t ws_size,
                              hipStream_t stream)
{
    const float* x     = (const float*)d_in[0];
    const float* Wqkv  = (const float*)d_in[1];
    const float* bqkv  = (const float*)d_in[2];
    const float* Wproj = (const float*)d_in[3];
    const float* bproj = (const float*)d_in[4];
    float* out = (float*)d_out;

    const size_t E  = (size_t)4096 * 768;        // 3,145,728
    const size_t WQ = (size_t)2304 * 768;        // 1,769,472
    const size_t WP = (size_t)768 * 768;         //   589,824

    u16* ws   = (u16*)d_ws;
    u16* atth = ws;            // aliases xh (x dead after qkv GEMM)
    u16* attl = ws + E;        // aliases xl
    u16* xh = atth;
    u16* xl = attl;
    u16* wqh = ws + 2 * E;
    u16* wql = wqh + WQ;
    u16* wph = wql + WQ;
    u16* wpl = wph + WP;
    u16* qh  = wpl + WP;
    u16* ql  = qh + E;
    u16* kh  = ql + E;
    u16* kl  = kh + E;
    u16* vth = kl + E;
    u16* vtl = vth + E;

    conv_split<<<dim3((int)(E / 4 / 256)), 256, 0, stream>>>(x, xh, xl);
    conv_tsplit<<<dim3(N3 / 64, CC / 64), 256, 0, stream>>>(Wqkv, wqh, wql, N3);
    conv_tsplit<<<dim3(CC / 64, CC / 64), 256, 0, stream>>>(Wproj, wph, wpl, CC);

    mm3<N3, 0><<<dim3(N3 / 128, 32), 256, 0, stream>>>(
        xh, xl, wqh, wql, bqkv, nullptr, qh, ql, kh, kl, vth, vtl);
    attn3<<<dim3(768), 256, 0, stream>>>(qh, ql, kh, kl, vth, vtl, atth, attl);
    mm3<CC, 1><<<dim3(CC / 128, 32), 256, 0, stream>>>(
        atth, attl, wph, wpl, bproj, out,
        nullptr, nullptr, nullptr, nullptr, nullptr, nullptr);
}

// Round 5
// 181.028 us; speedup vs baseline: 8.0315x; 1.4624x over previous
//
#include <hip/hip_runtime.h>
#include <math.h>

#define BB 2
#define TT 2048
#define CC 768
#define HH 12
#define HD 64
#define N3 (3*CC)

typedef __attribute__((ext_vector_type(8))) short short8;
typedef __attribute__((ext_vector_type(8))) _Float16 f16x8;
typedef __attribute__((ext_vector_type(4))) float f32x4;
typedef unsigned short u16;

static __device__ __forceinline__ u16 f2h(float x) {
    union { _Float16 h; u16 u; } v; v.h = (_Float16)x; return v.u;
}

// global -> LDS direct copy, 16B per lane. LDS dest = uniform base + lane*16.
static __device__ __forceinline__ void gl16(const void* g, void* l) {
    __builtin_amdgcn_global_load_lds(
        (const __attribute__((address_space(1))) void*)g,
        (__attribute__((address_space(3))) void*)l, 16, 0, 0);
}

// ---------------------------------------------------------------------------
// convert: fp32 row-major -> fp16 plane (same layout). One float4/thread.
// ---------------------------------------------------------------------------
__global__ __launch_bounds__(256)
void conv_h(const float* __restrict__ src, u16* __restrict__ dst)
{
    const int i = blockIdx.x * 256 + threadIdx.x;
    float4 v = ((const float4*)src)[i];
    ushort4 o;
    o.x = f2h(v.x); o.y = f2h(v.y); o.z = f2h(v.z); o.w = f2h(v.w);
    ((ushort4*)dst)[i] = o;
}

// ---------------------------------------------------------------------------
// convert + transpose: W[768][N] fp32 -> T [N][768] fp16. 64x64 tiles.
// ---------------------------------------------------------------------------
__global__ __launch_bounds__(256)
void conv_th(const float* __restrict__ W, u16* __restrict__ Th, int N)
{
    __shared__ float Tt[64][65];
    const int tid = threadIdx.x;
    const int n0 = blockIdx.x * 64, k0 = blockIdx.y * 64;
    {
        const int r = tid >> 2, q = tid & 3;
        #pragma unroll
        for (int i = 0; i < 4; ++i) {
            float4 v = *(const float4*)(W + (size_t)(k0 + r) * N + n0 + q * 16 + i * 4);
            Tt[q * 16 + i * 4 + 0][r] = v.x;
            Tt[q * 16 + i * 4 + 1][r] = v.y;
            Tt[q * 16 + i * 4 + 2][r] = v.z;
            Tt[q * 16 + i * 4 + 3][r] = v.w;
        }
    }
    __syncthreads();
    {
        const int n = tid >> 2, q = tid & 3;
        u16 hh[16];
        #pragma unroll
        for (int j = 0; j < 16; ++j) hh[j] = f2h(Tt[n][q * 16 + j]);
        u16* dh = Th + (size_t)(n0 + n) * 768 + k0 + q * 16;
        *(short8*)(dh) = *(short8*)&hh[0];
        *(short8*)(dh + 8) = *(short8*)&hh[8];
    }
}

// ---------------------------------------------------------------------------
// fp16 MFMA GEMM, 2-phase prefetch (T3-min). A [4096][768] fp16 plane,
// B [NCOLS][768] fp16 (pre-transposed). 128x128 tile, BK=32, 4 waves (2x2).
// MODE 0: epilogue -> fp16 q/k/v^T (+bias). MODE 1: fp32 out (+bias).
// ---------------------------------------------------------------------------
template<int NCOLS, int MODE>
__global__ __launch_bounds__(256)
void mm3(const u16* __restrict__ A_g, const u16* __restrict__ B_g,
         const float* __restrict__ bias, float* __restrict__ outF,
         u16* __restrict__ qo, u16* __restrict__ ko, u16* __restrict__ vto)
{
    __shared__ u16 gsm[16384];     // 32 KB: buf0 {A@0,B@8192}, buf1 @16384
    char* smb = (char*)gsm;
    const int tid = threadIdx.x, lane = tid & 63, wv = tid >> 6;
    const int wm = wv >> 1, wn = wv & 1, r16 = lane & 15, kg = lane >> 4;
    const int m0 = blockIdx.y * 128, n0 = blockIdx.x * 128;

    // staging: per-lane global pointers (source chunk-swizzled), uniform LDS base
    const u16 *pA[2], *pB[2];
    int ldsq[2];
    #pragma unroll
    for (int qq = 0; qq < 2; ++qq) {
        const int L = wv * 2048 + qq * 1024 + lane * 16;
        const int row = L >> 6, c = (L >> 4) & 3;
        const int cp = c ^ ((row >> 1) & 3);
        ldsq[qq] = wv * 2048 + qq * 1024;
        pA[qq] = A_g + (size_t)(m0 + row) * 768 + cp * 8;
        pB[qq] = B_g + (size_t)(n0 + row) * 768 + cp * 8;
    }

    // fragment ds_read byte addrs (buffer-relative, swizzled)
    int aA[4], aB[4];
    #pragma unroll
    for (int t = 0; t < 4; ++t) {
        const int rA = wm * 64 + t * 16 + r16;
        const int rB = wn * 64 + t * 16 + r16;
        aA[t] = rA * 64 + ((kg ^ ((rA >> 1) & 3)) << 4);
        aB[t] = rB * 64 + ((kg ^ ((rB >> 1) & 3)) << 4) + 8192;
    }

    f32x4 acc[4][4];
    #pragma unroll
    for (int i = 0; i < 4; ++i)
        #pragma unroll
        for (int j = 0; j < 4; ++j) acc[i][j] = (f32x4)0.f;

    // prologue: stage k-step 0 into buf0
    #pragma unroll
    for (int qq = 0; qq < 2; ++qq) {
        gl16(pA[qq], smb + ldsq[qq]);
        gl16(pB[qq], smb + 8192 + ldsq[qq]);
        pA[qq] += 32; pB[qq] += 32;
    }
    __syncthreads();

    int cur = 0;
    for (int ks = 0; ks < 24; ++ks) {
        const int nxt = cur ^ 1;
        if (ks != 23) {
            #pragma unroll
            for (int qq = 0; qq < 2; ++qq) {
                gl16(pA[qq], smb + nxt * 16384 + ldsq[qq]);
                gl16(pB[qq], smb + nxt * 16384 + 8192 + ldsq[qq]);
                pA[qq] += 32; pB[qq] += 32;
            }
        }
        const int cb = cur * 16384;
        f16x8 a[4], b[4];
        #pragma unroll
        for (int t = 0; t < 4; ++t) {
            a[t] = *(const f16x8*)(smb + cb + aA[t]);
            b[t] = *(const f16x8*)(smb + cb + aB[t]);
        }
        #pragma unroll
        for (int mt = 0; mt < 4; ++mt)
            #pragma unroll
            for (int nt = 0; nt < 4; ++nt)
                acc[mt][nt] = __builtin_amdgcn_mfma_f32_16x16x32_f16(a[mt], b[nt], acc[mt][nt], 0, 0, 0);
        __syncthreads();   // drains vmcnt(0): next buffer staged & ready
        cur = nxt;
    }

    float bi[4];
    #pragma unroll
    for (int nt = 0; nt < 4; ++nt) bi[nt] = bias[n0 + wn * 64 + nt * 16 + r16];

    if (MODE == 1) {
        #pragma unroll
        for (int mt = 0; mt < 4; ++mt)
            #pragma unroll
            for (int nt = 0; nt < 4; ++nt)
                #pragma unroll
                for (int r = 0; r < 4; ++r) {
                    const int grow = m0 + wm * 64 + mt * 16 + kg * 4 + r;
                    const int gcol = n0 + wn * 64 + nt * 16 + r16;
                    outF[(size_t)grow * CC + gcol] = acc[mt][nt][r] + bi[nt];
                }
    } else {
        const int which = n0 / CC;       // uniform per block
        const int b_ = m0 >> 11;
        #pragma unroll
        for (int mt = 0; mt < 4; ++mt) {
            const int tb = ((m0 & 2047) + wm * 64 + mt * 16 + kg * 4);
            #pragma unroll
            for (int nt = 0; nt < 4; ++nt) {
                const int gcol = n0 + wn * 64 + nt * 16 + r16;
                const int cc = gcol - which * CC;
                const int h = cc >> 6, d = cc & 63;
                const int bh_ = b_ * HH + h;
                if (which == 2) {
                    ushort4 hv;
                    #pragma unroll
                    for (int r = 0; r < 4; ++r)
                        ((u16*)&hv)[r] = f2h(acc[mt][nt][r] + bi[nt]);
                    *(ushort4*)(vto + ((size_t)bh_ * 64 + d) * 2048 + tb) = hv;
                } else {
                    u16* dst = (which == 0) ? qo : ko;
                    #pragma unroll
                    for (int r = 0; r < 4; ++r)
                        dst[(((size_t)bh_ * 2048 + tb + r) << 6) + d] =
                            f2h(acc[mt][nt][r] + bi[nt]);
                }
            }
        }
    }
}

// ---------------------------------------------------------------------------
// Flash attention, fp16 MFMA, 2-phase prefetch.
// Block = (bh, 64-row q-tile), 4 waves x 16 q-rows. K [key][d], V^T [d][key].
// ---------------------------------------------------------------------------
__global__ __launch_bounds__(256)
void attn3(const u16* __restrict__ qp, const u16* __restrict__ kp,
           const u16* __restrict__ vtp, u16* __restrict__ attp)
{
    __shared__ u16 smem[20480];  // 40 KB: buf0{K@0,V@8192} buf1@16384 P@32768
    char* smb = (char*)smem;

    const int tid = threadIdx.x, bid = blockIdx.x;
    const int qt = 31 - (bid / 24);          // long q-tiles dispatch first
    const int bh = bid % 24;
    const int lane = tid & 63, wv = tid >> 6;
    const int r16 = lane & 15, kg = lane >> 4;

    // Q fragments straight from global fp16 plane
    const size_t qro = ((size_t)bh * TT + qt * 64 + wv * 16 + r16) * 64;
    f16x8 qf[2];
    #pragma unroll
    for (int ks = 0; ks < 2; ++ks)
        qf[ks] = *(const f16x8*)(qp + qro + ks * 32 + kg * 8);

    // staging pointers (source chunk-swizzled)
    const u16 *pk[2], *pv[2];
    int ldsq[2];
    #pragma unroll
    for (int qq = 0; qq < 2; ++qq) {
        const int L = wv * 2048 + qq * 1024 + lane * 16;
        const int row = L >> 7, c = (L >> 4) & 7;
        const int cp = c ^ (row & 7);
        ldsq[qq] = wv * 2048 + qq * 1024;
        pk[qq] = kp + ((size_t)bh * TT + row) * 64 + cp * 8;     // +4096/tile
        pv[qq] = vtp + ((size_t)bh * 64 + row) * TT + cp * 8;    // +64/tile
    }

    // fragment ds_read byte addrs (buffer-relative, swizzled); K and V^T share
    int aK[2][4], aP[2];
    #pragma unroll
    for (int ks = 0; ks < 2; ++ks) {
        #pragma unroll
        for (int nt = 0; nt < 4; ++nt) {
            const int row = nt * 16 + r16;
            aK[ks][nt] = row * 128 + (((ks * 4 + kg) ^ (row & 7)) << 4);
        }
        aP[ks] = 32768 + wv * 2048 + r16 * 128 + (((ks * 4 + kg) ^ (r16 & 7)) << 4);
    }
    int pwb[4], pwx[4];
    #pragma unroll
    for (int r = 0; r < 4; ++r) {
        const int prow = kg * 4 + r;
        pwb[r] = 32768 + wv * 2048 + prow * 128;
        pwx[r] = (prow & 7) << 3;
    }

    f32x4 o_acc[4];
    #pragma unroll
    for (int i = 0; i < 4; ++i) o_acc[i] = (f32x4)0.f;
    float m_s[4] = {-1e30f, -1e30f, -1e30f, -1e30f};
    float l_s[4] = {0.f, 0.f, 0.f, 0.f};

    // prologue: stage tile 0 into buf0
    #pragma unroll
    for (int qq = 0; qq < 2; ++qq) {
        gl16(pk[qq], smb + ldsq[qq]);
        gl16(pv[qq], smb + 8192 + ldsq[qq]);
        pk[qq] += 4096; pv[qq] += 64;
    }
    __syncthreads();

    int cur = 0;
    for (int j = 0; j <= qt; ++j) {
        const int nxt = cur ^ 1;
        if (j != qt) {
            #pragma unroll
            for (int qq = 0; qq < 2; ++qq) {
                gl16(pk[qq], smb + nxt * 16384 + ldsq[qq]);
                gl16(pv[qq], smb + nxt * 16384 + 8192 + ldsq[qq]);
                pk[qq] += 4096; pv[qq] += 64;
            }
        }
        const int cb = cur * 16384;

        // S = Q K^T, then *1/sqrt(64)
        f32x4 s[4];
        #pragma unroll
        for (int nt = 0; nt < 4; ++nt) s[nt] = (f32x4)0.f;
        #pragma unroll
        for (int ks = 0; ks < 2; ++ks)
            #pragma unroll
            for (int nt = 0; nt < 4; ++nt) {
                f16x8 kf = *(const f16x8*)(smb + cb + aK[ks][nt]);
                s[nt] = __builtin_amdgcn_mfma_f32_16x16x32_f16(qf[ks], kf, s[nt], 0, 0, 0);
            }
        #pragma unroll
        for (int nt = 0; nt < 4; ++nt) s[nt] *= 0.125f;

        if (j == qt) {
            // causal: key-in-tile (nt*16+r16) vs query-in-tile (wv*16+kg*4+r)
            #pragma unroll
            for (int nt = 0; nt < 4; ++nt)
                #pragma unroll
                for (int r = 0; r < 4; ++r)
                    if (nt * 16 + r16 > wv * 16 + kg * 4 + r) s[nt][r] = -1e30f;
        }

        // online softmax (row lives in a 16-lane group)
        #pragma unroll
        for (int r = 0; r < 4; ++r) {
            float mx = fmaxf(fmaxf(s[0][r], s[1][r]), fmaxf(s[2][r], s[3][r]));
            mx = fmaxf(mx, __shfl_xor(mx, 1));
            mx = fmaxf(mx, __shfl_xor(mx, 2));
            mx = fmaxf(mx, __shfl_xor(mx, 4));
            mx = fmaxf(mx, __shfl_xor(mx, 8));
            const float mn = fmaxf(m_s[r], mx);
            const float corr = __expf(m_s[r] - mn);
            float ps = 0.f;
            #pragma unroll
            for (int nt = 0; nt < 4; ++nt) {
                const float p = __expf(s[nt][r] - mn);
                s[nt][r] = p;
                ps += p;
            }
            ps += __shfl_xor(ps, 1);
            ps += __shfl_xor(ps, 2);
            ps += __shfl_xor(ps, 4);
            ps += __shfl_xor(ps, 8);
            l_s[r] = l_s[r] * corr + ps;
            m_s[r] = mn;
            #pragma unroll
            for (int nt = 0; nt < 4; ++nt) o_acc[nt][r] *= corr;
        }

        // P -> fp16, swizzled wave-local LDS round trip
        #pragma unroll
        for (int nt = 0; nt < 4; ++nt)
            #pragma unroll
            for (int r = 0; r < 4; ++r)
                *(u16*)(smb + pwb[r] + (((nt * 16 + r16) ^ pwx[r]) << 1)) = f2h(s[nt][r]);

        // O += P @ V
        #pragma unroll
        for (int ks = 0; ks < 2; ++ks) {
            f16x8 pa = *(const f16x8*)(smb + aP[ks]);
            #pragma unroll
            for (int nt = 0; nt < 4; ++nt) {
                f16x8 vf = *(const f16x8*)(smb + cb + 8192 + aK[ks][nt]);
                o_acc[nt] = __builtin_amdgcn_mfma_f32_16x16x32_f16(pa, vf, o_acc[nt], 0, 0, 0);
            }
        }

        __syncthreads();   // drains vmcnt(0): next buffer ready; frees cur buffer
        cur = nxt;
    }

    // epilogue: normalize, write att fp16 plane [B*T][C]
    const int b_ = bh / HH, h = bh % HH;
    #pragma unroll
    for (int r = 0; r < 4; ++r) {
        const float inv = 1.f / l_s[r];
        const int t = qt * 64 + wv * 16 + kg * 4 + r;
        const size_t base = ((size_t)b_ * TT + t) * CC + h * 64;
        #pragma unroll
        for (int nt = 0; nt < 4; ++nt)
            attp[base + nt * 16 + r16] = f2h(o_acc[nt][r] * inv);
    }
}

// ---------------------------------------------------------------------------
extern "C" void kernel_launch(void* const* d_in, const int* in_sizes, int n_in,
                              void* d_out, int out_size, void* d_ws, size_t ws_size,
                              hipStream_t stream)
{
    const float* x     = (const float*)d_in[0];
    const float* Wqkv  = (const float*)d_in[1];
    const float* bqkv  = (const float*)d_in[2];
    const float* Wproj = (const float*)d_in[3];
    const float* bproj = (const float*)d_in[4];
    float* out = (float*)d_out;

    const size_t E  = (size_t)4096 * 768;        // 3,145,728
    const size_t WQ = (size_t)2304 * 768;
    const size_t WP = (size_t)768 * 768;

    u16* ws   = (u16*)d_ws;
    u16* xh   = ws;            // x plane; aliased by att plane after qkv GEMM
    u16* atth = ws;
    u16* wqh  = ws + E;
    u16* wph  = wqh + WQ;
    u16* qh   = wph + WP;
    u16* kh   = qh + E;
    u16* vth  = kh + E;

    conv_h<<<dim3((int)(E / 4 / 256)), 256, 0, stream>>>(x, xh);
    conv_th<<<dim3(N3 / 64, CC / 64), 256, 0, stream>>>(Wqkv, wqh, N3);
    conv_th<<<dim3(CC / 64, CC / 64), 256, 0, stream>>>(Wproj, wph, CC);

    mm3<N3, 0><<<dim3(N3 / 128, 32), 256, 0, stream>>>(
        xh, wqh, bqkv, nullptr, qh, kh, vth);
    attn3<<<dim3(768), 256, 0, stream>>>(qh, kh, vth, atth);
    mm3<CC, 1><<<dim3(CC / 128, 32), 256, 0, stream>>>(
        atth, wph, bproj, out, nullptr, nullptr, nullptr);
}

// Round 7
// 156.183 us; speedup vs baseline: 9.3091x; 1.1591x over previous
//
#include <hip/hip_runtime.h>
#include <math.h>

#define BB 2
#define TT 2048
#define CC 768
#define HH 12
#define HD 64
#define N3 (3*CC)

typedef __attribute__((ext_vector_type(8))) short short8;
typedef __attribute__((ext_vector_type(8))) _Float16 f16x8;
typedef __attribute__((ext_vector_type(4))) float f32x4;
typedef unsigned short u16;

// scale folded into q: 1/sqrt(64) * log2(e)
#define QSCALE 0.1803368809f

static __device__ __forceinline__ u16 f2h(float x) {
    union { _Float16 h; u16 u; } v; v.h = (_Float16)x; return v.u;
}
static __device__ __forceinline__ float ex2(float x) {
#if __has_builtin(__builtin_amdgcn_exp2f)
    return __builtin_amdgcn_exp2f(x);
#else
    return exp2f(x);
#endif
}
// pack two f32 -> 2x fp16 (round-toward-zero), as raw u32
static __device__ __forceinline__ unsigned pk2h(float a, float b) {
    auto p = __builtin_amdgcn_cvt_pkrtz(a, b);   // __fp16 ext_vector(2)
    return __builtin_bit_cast(unsigned, p);
}

// global -> LDS direct copy, 16B per lane. LDS dest = uniform base + lane*16.
static __device__ __forceinline__ void gl16(const void* g, void* l) {
    __builtin_amdgcn_global_load_lds(
        (const __attribute__((address_space(1))) void*)g,
        (__attribute__((address_space(3))) void*)l, 16, 0, 0);
}

// ---------------------------------------------------------------------------
// convert: fp32 row-major -> fp16 plane (same layout). One float4/thread.
// ---------------------------------------------------------------------------
__global__ __launch_bounds__(256)
void conv_h(const float* __restrict__ src, u16* __restrict__ dst)
{
    const int i = blockIdx.x * 256 + threadIdx.x;
    float4 v = ((const float4*)src)[i];
    ushort4 o;
    o.x = f2h(v.x); o.y = f2h(v.y); o.z = f2h(v.z); o.w = f2h(v.w);
    ((ushort4*)dst)[i] = o;
}

// ---------------------------------------------------------------------------
// convert + transpose: W[768][N] fp32 -> T [N][768] fp16. 64x64 tiles.
// ---------------------------------------------------------------------------
__global__ __launch_bounds__(256)
void conv_th(const float* __restrict__ W, u16* __restrict__ Th, int N)
{
    __shared__ float Tt[64][65];
    const int tid = threadIdx.x;
    const int n0 = blockIdx.x * 64, k0 = blockIdx.y * 64;
    {
        const int r = tid >> 2, q = tid & 3;
        #pragma unroll
        for (int i = 0; i < 4; ++i) {
            float4 v = *(const float4*)(W + (size_t)(k0 + r) * N + n0 + q * 16 + i * 4);
            Tt[q * 16 + i * 4 + 0][r] = v.x;
            Tt[q * 16 + i * 4 + 1][r] = v.y;
            Tt[q * 16 + i * 4 + 2][r] = v.z;
            Tt[q * 16 + i * 4 + 3][r] = v.w;
        }
    }
    __syncthreads();
    {
        const int n = tid >> 2, q = tid & 3;
        u16 hh[16];
        #pragma unroll
        for (int j = 0; j < 16; ++j) hh[j] = f2h(Tt[n][q * 16 + j]);
        u16* dh = Th + (size_t)(n0 + n) * 768 + k0 + q * 16;
        *(short8*)(dh) = *(short8*)&hh[0];
        *(short8*)(dh + 8) = *(short8*)&hh[8];
    }
}

// ---------------------------------------------------------------------------
// fp16 MFMA GEMM, 2-phase prefetch. A [4096][768] fp16 plane,
// B [NCOLS][768] fp16 (pre-transposed). 128x128 tile, BK=32, 4 waves (2x2).
// MODE 0: epilogue -> fp16 q/k/v^T (+bias; q pre-scaled by QSCALE).
// MODE 1: fp32 out (+bias).
// ---------------------------------------------------------------------------
template<int NCOLS, int MODE>
__global__ __launch_bounds__(256)
void mm3(const u16* __restrict__ A_g, const u16* __restrict__ B_g,
         const float* __restrict__ bias, float* __restrict__ outF,
         u16* __restrict__ qo, u16* __restrict__ ko, u16* __restrict__ vto)
{
    __shared__ u16 gsm[16384];     // 32 KB: buf0 {A@0,B@8192}, buf1 @16384
    char* smb = (char*)gsm;
    const int tid = threadIdx.x, lane = tid & 63, wv = tid >> 6;
    const int wm = wv >> 1, wn = wv & 1, r16 = lane & 15, kg = lane >> 4;
    const int m0 = blockIdx.y * 128, n0 = blockIdx.x * 128;

    // staging: per-lane global pointers (source chunk-swizzled), uniform LDS base
    const u16 *pA[2], *pB[2];
    int ldsq[2];
    #pragma unroll
    for (int qq = 0; qq < 2; ++qq) {
        const int L = wv * 2048 + qq * 1024 + lane * 16;
        const int row = L >> 6, c = (L >> 4) & 3;
        const int cp = c ^ ((row >> 1) & 3);
        ldsq[qq] = wv * 2048 + qq * 1024;
        pA[qq] = A_g + (size_t)(m0 + row) * 768 + cp * 8;
        pB[qq] = B_g + (size_t)(n0 + row) * 768 + cp * 8;
    }

    // fragment ds_read byte addrs (buffer-relative, swizzled)
    int aA[4], aB[4];
    #pragma unroll
    for (int t = 0; t < 4; ++t) {
        const int rA = wm * 64 + t * 16 + r16;
        const int rB = wn * 64 + t * 16 + r16;
        aA[t] = rA * 64 + ((kg ^ ((rA >> 1) & 3)) << 4);
        aB[t] = rB * 64 + ((kg ^ ((rB >> 1) & 3)) << 4) + 8192;
    }

    f32x4 acc[4][4];
    #pragma unroll
    for (int i = 0; i < 4; ++i)
        #pragma unroll
        for (int j = 0; j < 4; ++j) acc[i][j] = (f32x4)0.f;

    // prologue: stage k-step 0 into buf0
    #pragma unroll
    for (int qq = 0; qq < 2; ++qq) {
        gl16(pA[qq], smb + ldsq[qq]);
        gl16(pB[qq], smb + 8192 + ldsq[qq]);
        pA[qq] += 32; pB[qq] += 32;
    }
    __syncthreads();

    int cur = 0;
    for (int ks = 0; ks < 24; ++ks) {
        const int nxt = cur ^ 1;
        if (ks != 23) {
            #pragma unroll
            for (int qq = 0; qq < 2; ++qq) {
                gl16(pA[qq], smb + nxt * 16384 + ldsq[qq]);
                gl16(pB[qq], smb + nxt * 16384 + 8192 + ldsq[qq]);
                pA[qq] += 32; pB[qq] += 32;
            }
        }
        const int cb = cur * 16384;
        f16x8 a[4], b[4];
        #pragma unroll
        for (int t = 0; t < 4; ++t) {
            a[t] = *(const f16x8*)(smb + cb + aA[t]);
            b[t] = *(const f16x8*)(smb + cb + aB[t]);
        }
        #pragma unroll
        for (int mt = 0; mt < 4; ++mt)
            #pragma unroll
            for (int nt = 0; nt < 4; ++nt)
                acc[mt][nt] = __builtin_amdgcn_mfma_f32_16x16x32_f16(a[mt], b[nt], acc[mt][nt], 0, 0, 0);
        __syncthreads();   // drains vmcnt(0): next buffer staged & ready
        cur = nxt;
    }

    float bi[4];
    #pragma unroll
    for (int nt = 0; nt < 4; ++nt) bi[nt] = bias[n0 + wn * 64 + nt * 16 + r16];

    if (MODE == 1) {
        #pragma unroll
        for (int mt = 0; mt < 4; ++mt)
            #pragma unroll
            for (int nt = 0; nt < 4; ++nt)
                #pragma unroll
                for (int r = 0; r < 4; ++r) {
                    const int grow = m0 + wm * 64 + mt * 16 + kg * 4 + r;
                    const int gcol = n0 + wn * 64 + nt * 16 + r16;
                    outF[(size_t)grow * CC + gcol] = acc[mt][nt][r] + bi[nt];
                }
    } else {
        const int which = n0 / CC;       // uniform per block
        const float qsc = (which == 0) ? QSCALE : 1.0f;
        const int b_ = m0 >> 11;
        #pragma unroll
        for (int mt = 0; mt < 4; ++mt) {
            const int tb = ((m0 & 2047) + wm * 64 + mt * 16 + kg * 4);
            #pragma unroll
            for (int nt = 0; nt < 4; ++nt) {
                const int gcol = n0 + wn * 64 + nt * 16 + r16;
                const int cc = gcol - which * CC;
                const int h = cc >> 6, d = cc & 63;
                const int bh_ = b_ * HH + h;
                if (which == 2) {
                    ushort4 hv;
                    #pragma unroll
                    for (int r = 0; r < 4; ++r)
                        ((u16*)&hv)[r] = f2h(acc[mt][nt][r] + bi[nt]);
                    *(ushort4*)(vto + ((size_t)bh_ * 64 + d) * 2048 + tb) = hv;
                } else {
                    u16* dst = (which == 0) ? qo : ko;
                    #pragma unroll
                    for (int r = 0; r < 4; ++r)
                        dst[(((size_t)bh_ * 2048 + tb + r) << 6) + d] =
                            f2h((acc[mt][nt][r] + bi[nt]) * qsc);
                }
            }
        }
    }
}

// ---------------------------------------------------------------------------
// Flash attention, fp16 MFMA, 2-phase prefetch, swapped-QK^T softmax.
// Block = (bh, 64-row q-tile), 4 waves x 16 q-rows. K [key][d], V^T [d][key].
// S^T = mfma(K, Q): lane owns one q-row (wv*16+r16), 16 keys in-reg.
// l via ones-column MFMA; defer-max (THR=8, log2 units).
// ---------------------------------------------------------------------------
__global__ __launch_bounds__(256)
void attn3(const u16* __restrict__ qp, const u16* __restrict__ kp,
           const u16* __restrict__ vtp, u16* __restrict__ attp)
{
    __shared__ u16 smem[20480];  // 40 KB: buf0{K@0,V@8192} buf1@16384 P@32768
    char* smb = (char*)smem;

    const int tid = threadIdx.x, bid = blockIdx.x;
    const int qt = 31 - (bid / 24);          // long q-tiles dispatch first
    const int bh = bid % 24;
    const int lane = tid & 63, wv = tid >> 6;
    const int r16 = lane & 15, kg = lane >> 4;
    const int r7 = r16 & 7;

    // Q fragments straight from global fp16 plane (pre-scaled by QSCALE)
    const size_t qro = ((size_t)bh * TT + qt * 64 + wv * 16 + r16) * 64;
    f16x8 qf[2];
    #pragma unroll
    for (int ks = 0; ks < 2; ++ks)
        qf[ks] = *(const f16x8*)(qp + qro + ks * 32 + kg * 8);

    // staging pointers (source chunk-swizzled)
    const u16 *pk[2], *pv[2];
    int ldsq[2];
    #pragma unroll
    for (int qq = 0; qq < 2; ++qq) {
        const int L = wv * 2048 + qq * 1024 + lane * 16;
        const int row = L >> 7, c = (L >> 4) & 7;
        const int cp = c ^ (row & 7);
        ldsq[qq] = wv * 2048 + qq * 1024;
        pk[qq] = kp + ((size_t)bh * TT + row) * 64 + cp * 8;     // +4096/tile
        pv[qq] = vtp + ((size_t)bh * 64 + row) * TT + cp * 8;    // +64/tile
    }

    // fragment ds_read byte addrs (buffer-relative, swizzled); K and V^T share
    int aK[2][4], aP[2];
    #pragma unroll
    for (int ks = 0; ks < 2; ++ks) {
        #pragma unroll
        for (int nt = 0; nt < 4; ++nt) {
            const int row = nt * 16 + r16;
            aK[ks][nt] = row * 128 + (((ks * 4 + kg) ^ (row & 7)) << 4);
        }
        aP[ks] = 32768 + wv * 2048 + r16 * 128 + (((ks * 4 + kg) ^ r7) << 4);
    }
    const int pwbase = 32768 + wv * 2048 + r16 * 128;   // P write: row = own q-row
    const int kg8 = kg * 8, kg4 = kg * 4;

    f32x4 o_acc[4];
    #pragma unroll
    for (int i = 0; i < 4; ++i) o_acc[i] = (f32x4)0.f;
    f32x4 o_l = (f32x4)0.f;          // row-sums of P via ones-MFMA
    float m = -1e30f;                // running max (log2 units), row wv*16+r16

    f16x8 ones;
    #pragma unroll
    for (int i = 0; i < 8; ++i) ones[i] = (_Float16)1.0f;

    // prologue: stage tile 0 into buf0
    #pragma unroll
    for (int qq = 0; qq < 2; ++qq) {
        gl16(pk[qq], smb + ldsq[qq]);
        gl16(pv[qq], smb + 8192 + ldsq[qq]);
        pk[qq] += 4096; pv[qq] += 64;
    }
    __syncthreads();

    int cur = 0;
    for (int j = 0; j <= qt; ++j) {
        const int nxt = cur ^ 1;
        if (j != qt) {
            #pragma unroll
            for (int qq = 0; qq < 2; ++qq) {
                gl16(pk[qq], smb + nxt * 16384 + ldsq[qq]);
                gl16(pv[qq], smb + nxt * 16384 + 8192 + ldsq[qq]);
                pk[qq] += 4096; pv[qq] += 64;
            }
        }
        const int cb = cur * 16384;

        // S^T = K (Q*scale)^T : s[nt][r] = S[key=nt*16+kg*4+r][qrow=wv*16+r16]
        f32x4 s[4];
        #pragma unroll
        for (int nt = 0; nt < 4; ++nt) s[nt] = (f32x4)0.f;
        __builtin_amdgcn_s_setprio(1);
        #pragma unroll
        for (int ks = 0; ks < 2; ++ks)
            #pragma unroll
            for (int nt = 0; nt < 4; ++nt) {
                f16x8 kf = *(const f16x8*)(smb + cb + aK[ks][nt]);
                s[nt] = __builtin_amdgcn_mfma_f32_16x16x32_f16(kf, qf[ks], s[nt], 0, 0, 0);
            }
        __builtin_amdgcn_s_setprio(0);

        if (j == qt) {
            // causal: key (nt*16+kg*4+r) vs q-row (wv*16+r16)
            #pragma unroll
            for (int nt = 0; nt < 4; ++nt)
                #pragma unroll
                for (int r = 0; r < 4; ++r)
                    if (nt * 16 + kg4 + r > wv * 16 + r16) s[nt][r] = -1e30f;
        }

        // row max: 15 in-reg fmax + 2 shuffles (combine kg groups)
        float pm = s[0][0];
        #pragma unroll
        for (int nt = 0; nt < 4; ++nt)
            #pragma unroll
            for (int r = 0; r < 4; ++r)
                if (nt | r) pm = fmaxf(pm, s[nt][r]);
        pm = fmaxf(pm, __shfl_xor(pm, 16));
        pm = fmaxf(pm, __shfl_xor(pm, 32));

        // defer-max: rescale only when some row grew past THR=8 (P <= 2^8)
        if (__any(pm > m + 8.0f)) {
            const float mn = fmaxf(m, pm);
            const float corr = ex2(m - mn);
            m = mn;
            // o rows are kg*4+r; corr for row rr lives on lane rr (kg=0 group)
            const float c0 = __shfl(corr, kg4 + 0);
            const float c1 = __shfl(corr, kg4 + 1);
            const float c2 = __shfl(corr, kg4 + 2);
            const float c3 = __shfl(corr, kg4 + 3);
            #pragma unroll
            for (int nt = 0; nt < 4; ++nt) {
                o_acc[nt][0] *= c0; o_acc[nt][1] *= c1;
                o_acc[nt][2] *= c2; o_acc[nt][3] *= c3;
            }
            o_l[0] *= c0; o_l[1] *= c1; o_l[2] *= c2; o_l[3] *= c3;
        }

        // P = 2^(s-m) -> fp16 pairs, packed b64 writes (row r16, keys in-lane)
        #pragma unroll
        for (int nt = 0; nt < 4; ++nt) {
            const float p0 = ex2(s[nt][0] - m), p1 = ex2(s[nt][1] - m);
            const float p2 = ex2(s[nt][2] - m), p3 = ex2(s[nt][3] - m);
            uint2 w;
            w.x = pk2h(p0, p1);
            w.y = pk2h(p2, p3);
            *(uint2*)(smb + pwbase + ((nt * 32 + kg8) ^ (r7 << 4))) = w;
        }

        // O += P @ V ; l += P @ ones
        __builtin_amdgcn_s_setprio(1);
        #pragma unroll
        for (int ks = 0; ks < 2; ++ks) {
            f16x8 pa = *(const f16x8*)(smb + aP[ks]);
            o_l = __builtin_amdgcn_mfma_f32_16x16x32_f16(pa, ones, o_l, 0, 0, 0);
            #pragma unroll
            for (int nt = 0; nt < 4; ++nt) {
                f16x8 vf = *(const f16x8*)(smb + cb + 8192 + aK[ks][nt]);
                o_acc[nt] = __builtin_amdgcn_mfma_f32_16x16x32_f16(pa, vf, o_acc[nt], 0, 0, 0);
            }
        }
        __builtin_amdgcn_s_setprio(0);

        __syncthreads();   // drains vmcnt(0): next buffer ready; frees cur buffer
        cur = nxt;
    }

    // epilogue: normalize, write att fp16 plane [B*T][C]
    const int b_ = bh / HH, h = bh % HH;
    #pragma unroll
    for (int r = 0; r < 4; ++r) {
        const float inv = 1.f / o_l[r];
        const int t = qt * 64 + wv * 16 + kg4 + r;
        const size_t base = ((size_t)b_ * TT + t) * CC + h * 64;
        #pragma unroll
        for (int nt = 0; nt < 4; ++nt)
            attp[base + nt * 16 + r16] = f2h(o_acc[nt][r] * inv);
    }
}

// ---------------------------------------------------------------------------
extern "C" void kernel_launch(void* const* d_in, const int* in_sizes, int n_in,
                              void* d_out, int out_size, void* d_ws, size_t ws_size,
                              hipStream_t stream)
{
    const float* x     = (const float*)d_in[0];
    const float* Wqkv  = (const float*)d_in[1];
    const float* bqkv  = (const float*)d_in[2];
    const float* Wproj = (const float*)d_in[3];
    const float* bproj = (const float*)d_in[4];
    float* out = (float*)d_out;

    const size_t E  = (size_t)4096 * 768;        // 3,145,728
    const size_t WQ = (size_t)2304 * 768;
    const size_t WP = (size_t)768 * 768;

    u16* ws   = (u16*)d_ws;
    u16* xh   = ws;            // x plane; aliased by att plane after qkv GEMM
    u16* atth = ws;
    u16* wqh  = ws + E;
    u16* wph  = wqh + WQ;
    u16* qh   = wph + WP;
    u16* kh   = qh + E;
    u16* vth  = kh + E;

    conv_h<<<dim3((int)(E / 4 / 256)), 256, 0, stream>>>(x, xh);
    conv_th<<<dim3(N3 / 64, CC / 64), 256, 0, stream>>>(Wqkv, wqh, N3);
    conv_th<<<dim3(CC / 64, CC / 64), 256, 0, stream>>>(Wproj, wph, CC);

    mm3<N3, 0><<<dim3(N3 / 128, 32), 256, 0, stream>>>(
        xh, wqh, bqkv, nullptr, qh, kh, vth);
    attn3<<<dim3(768), 256, 0, stream>>>(qh, kh, vth, atth);
    mm3<CC, 1><<<dim3(CC / 128, 32), 256, 0, stream>>>(
        atth, wph, bproj, out, nullptr, nullptr, nullptr);
}